// Round 1
// baseline (1819.764 us; speedup 1.0000x reference)
//
#include <hip/hip_runtime.h>
#include <math.h>

// Problem constants (fixed by reference)
#define B_    16
#define C_    512      // CIN == COUT
#define N_    4096     // H*W
#define M_    192      // NSR*K codebook size
#define EPS_BN 1e-5f
#define CNT_  ((float)(B_ * N_))   // BN reduction count = 65536

// ---------------------------------------------------------------------------
// Generic 128x128x8 fp32 SGEMM for the 1x1 convs:
//   Y[b][o][n] = sum_c W[o][c] * X[b][c][n] (+ bias[o])
// grid = (N_/128, C_/128, B_), block = 256
// ---------------------------------------------------------------------------
__global__ __launch_bounds__(256) void gemm_wx(
    const float* __restrict__ W, const float* __restrict__ X,
    float* __restrict__ Y, const float* __restrict__ bias) {
  const int tid = threadIdx.x;
  const int bn = blockIdx.x * 128;            // n tile offset
  const int bm = blockIdx.y * 128;            // o tile offset
  const float* Xb = X + (size_t)blockIdx.z * C_ * N_;
  float*       Yb = Y + (size_t)blockIdx.z * C_ * N_;

  __shared__ float As[8][128];   // [k][m]
  __shared__ float Bs[8][128];   // [k][n]

  float acc[8][8];
#pragma unroll
  for (int i = 0; i < 8; ++i)
#pragma unroll
    for (int j = 0; j < 8; ++j) acc[i][j] = 0.0f;

  const int tm = (tid >> 4) << 3;     // 0..120
  const int tn = (tid & 15) << 3;     // 0..120
  const int a_row = tid >> 1;         // 0..127  (o)
  const int a_col = (tid & 1) << 2;   // 0 or 4  (k)
  const int b_row = tid >> 5;         // 0..7    (k)
  const int b_col = (tid & 31) << 2;  // 0..124  (n)

  for (int k0 = 0; k0 < C_; k0 += 8) {
    float4 av = *(const float4*)(W + (size_t)(bm + a_row) * C_ + k0 + a_col);
    float4 bv = *(const float4*)(Xb + (size_t)(k0 + b_row) * N_ + bn + b_col);
    As[a_col + 0][a_row] = av.x;
    As[a_col + 1][a_row] = av.y;
    As[a_col + 2][a_row] = av.z;
    As[a_col + 3][a_row] = av.w;
    *(float4*)(&Bs[b_row][b_col]) = bv;
    __syncthreads();
#pragma unroll
    for (int kk = 0; kk < 8; ++kk) {
      float ar[8], br[8];
#pragma unroll
      for (int i = 0; i < 8; ++i) ar[i] = As[kk][tm + i];
#pragma unroll
      for (int j = 0; j < 8; ++j) br[j] = Bs[kk][tn + j];
#pragma unroll
      for (int i = 0; i < 8; ++i)
#pragma unroll
        for (int j = 0; j < 8; ++j) acc[i][j] = fmaf(ar[i], br[j], acc[i][j]);
    }
    __syncthreads();
  }

#pragma unroll
  for (int i = 0; i < 8; ++i) {
    const float bvv = bias ? bias[bm + tm + i] : 0.0f;
    float4 o0 = make_float4(acc[i][0] + bvv, acc[i][1] + bvv,
                            acc[i][2] + bvv, acc[i][3] + bvv);
    float4 o1 = make_float4(acc[i][4] + bvv, acc[i][5] + bvv,
                            acc[i][6] + bvv, acc[i][7] + bvv);
    float* dst = Yb + (size_t)(bm + tm + i) * N_ + bn + tn;
    *(float4*)(dst)     = o0;
    *(float4*)(dst + 4) = o1;
  }
}

// ---------------------------------------------------------------------------
// Attention logits: att[b][n][k] = sum_c x1[b][c][n] * centers[c][k]
// A^T access on x1 (n contiguous), B = centers row-major [c][k].
// 128(n) x 64(k) tile, BK=8. grid = (N_/128, M_/64, B_), block = 256
// ---------------------------------------------------------------------------
__global__ __launch_bounds__(256) void gemm_att(
    const float* __restrict__ X1, const float* __restrict__ Cent,
    float* __restrict__ Att) {
  const int tid = threadIdx.x;
  const int bn = blockIdx.x * 128;   // n offset
  const int bk = blockIdx.y * 64;    // codebook offset
  const float* Xb = X1 + (size_t)blockIdx.z * C_ * N_;

  __shared__ float As[8][128];   // [c][n]
  __shared__ float Bs[8][64];    // [c][k]

  float acc[8][4];
#pragma unroll
  for (int i = 0; i < 8; ++i)
#pragma unroll
    for (int j = 0; j < 4; ++j) acc[i][j] = 0.0f;

  const int tm = (tid >> 4) << 3;    // n 0..120
  const int tn = (tid & 15) << 2;    // k 0..60
  const int a_kc = tid >> 5;           // 0..7
  const int a_m4 = (tid & 31) << 2;    // 0..124
  const int b_kc = tid >> 5;           // 0..7
  const int b_c2 = (tid & 31) << 1;    // 0..62

  for (int k0 = 0; k0 < C_; k0 += 8) {
    *(float4*)&As[a_kc][a_m4] =
        *(const float4*)(Xb + (size_t)(k0 + a_kc) * N_ + bn + a_m4);
    *(float2*)&Bs[b_kc][b_c2] =
        *(const float2*)(Cent + (size_t)(k0 + b_kc) * M_ + bk + b_c2);
    __syncthreads();
#pragma unroll
    for (int kk = 0; kk < 8; ++kk) {
      float ar[8], br[4];
#pragma unroll
      for (int i = 0; i < 8; ++i) ar[i] = As[kk][tm + i];
#pragma unroll
      for (int j = 0; j < 4; ++j) br[j] = Bs[kk][tn + j];
#pragma unroll
      for (int i = 0; i < 8; ++i)
#pragma unroll
        for (int j = 0; j < 4; ++j) acc[i][j] = fmaf(ar[i], br[j], acc[i][j]);
    }
    __syncthreads();
  }

#pragma unroll
  for (int i = 0; i < 8; ++i) {
    float4 o = make_float4(acc[i][0], acc[i][1], acc[i][2], acc[i][3]);
    *(float4*)(Att + ((size_t)blockIdx.z * N_ + bn + tm + i) * M_ + bk + tn) = o;
  }
}

// ---------------------------------------------------------------------------
// Row softmax over k (192), in place. One wave per row, 4 waves per block.
// grid = B_*N_/4
// ---------------------------------------------------------------------------
__global__ __launch_bounds__(256) void softmax_rows(float* __restrict__ Att) {
  const int wid  = threadIdx.x >> 6;
  const int lane = threadIdx.x & 63;
  const size_t row = (size_t)blockIdx.x * 4 + wid;
  float* p = Att + row * M_;
  float v0 = p[lane], v1 = p[lane + 64], v2 = p[lane + 128];
  float m = fmaxf(v0, fmaxf(v1, v2));
#pragma unroll
  for (int off = 32; off; off >>= 1) m = fmaxf(m, __shfl_xor(m, off));
  v0 = __expf(v0 - m);
  v1 = __expf(v1 - m);
  v2 = __expf(v2 - m);
  float s = v0 + v1 + v2;
#pragma unroll
  for (int off = 32; off; off >>= 1) s += __shfl_xor(s, off);
  const float r = 1.0f / s;
  p[lane]       = v0 * r;
  p[lane + 64]  = v1 * r;
  p[lane + 128] = v2 * r;
}

// ---------------------------------------------------------------------------
// Column sums over n for double normalization: Cs[b][k] = sum_n att[b][n][k]
// grid = (16 n-chunks, B_), block = 256 (threads 0..191 active)
// ---------------------------------------------------------------------------
__global__ __launch_bounds__(256) void colsum_kernel(
    const float* __restrict__ Att, float* __restrict__ Cs) {
  const int b  = blockIdx.y;
  const int n0 = blockIdx.x * 256;
  const int k  = threadIdx.x;
  if (k < M_) {
    float s = 0.0f;
    const float* p = Att + ((size_t)b * N_ + n0) * M_ + k;
    for (int n = 0; n < 256; ++n) s += p[(size_t)n * M_];
    atomicAdd(&Cs[b * M_ + k], s);
  }
}

// ---------------------------------------------------------------------------
// Reconstruction: Xre[b][c][n] = sum_k centers[c][k] * att[b][n][k]/(1e-6+Cs[b][k])
// 128(c) x 128(n), K = 192, BK = 8. grid = (N_/128, C_/128, B_)
// ---------------------------------------------------------------------------
__global__ __launch_bounds__(256) void gemm_xre(
    const float* __restrict__ Cent, const float* __restrict__ Att,
    const float* __restrict__ Cs, float* __restrict__ Xre) {
  const int tid = threadIdx.x;
  const int bn = blockIdx.x * 128;   // n
  const int bm = blockIdx.y * 128;   // c
  const int b  = blockIdx.z;

  __shared__ float As[8][128];   // [k][c]
  __shared__ float Bs[8][128];   // [k][n]
  __shared__ float inv[M_];

  if (tid < M_) inv[tid] = 1.0f / (1e-6f + Cs[b * M_ + tid]);
  __syncthreads();

  float acc[8][8];
#pragma unroll
  for (int i = 0; i < 8; ++i)
#pragma unroll
    for (int j = 0; j < 8; ++j) acc[i][j] = 0.0f;

  const int tm = (tid >> 4) << 3;
  const int tn = (tid & 15) << 3;
  const int a_row = tid >> 1;          // c row 0..127
  const int a_col = (tid & 1) << 2;    // k 0/4
  const int b_row = tid >> 1;          // n row 0..127
  const int b_col = (tid & 1) << 2;    // k 0/4

  for (int k0 = 0; k0 < M_; k0 += 8) {
    float4 av = *(const float4*)(Cent + (size_t)(bm + a_row) * M_ + k0 + a_col);
    As[a_col + 0][a_row] = av.x;
    As[a_col + 1][a_row] = av.y;
    As[a_col + 2][a_row] = av.z;
    As[a_col + 3][a_row] = av.w;
    float4 bv = *(const float4*)(Att + ((size_t)b * N_ + bn + b_row) * M_ + k0 + b_col);
    Bs[b_col + 0][b_row] = bv.x * inv[k0 + b_col + 0];
    Bs[b_col + 1][b_row] = bv.y * inv[k0 + b_col + 1];
    Bs[b_col + 2][b_row] = bv.z * inv[k0 + b_col + 2];
    Bs[b_col + 3][b_row] = bv.w * inv[k0 + b_col + 3];
    __syncthreads();
#pragma unroll
    for (int kk = 0; kk < 8; ++kk) {
      float ar[8], br[8];
#pragma unroll
      for (int i = 0; i < 8; ++i) ar[i] = As[kk][tm + i];
#pragma unroll
      for (int j = 0; j < 8; ++j) br[j] = Bs[kk][tn + j];
#pragma unroll
      for (int i = 0; i < 8; ++i)
#pragma unroll
        for (int j = 0; j < 8; ++j) acc[i][j] = fmaf(ar[i], br[j], acc[i][j]);
    }
    __syncthreads();
  }

#pragma unroll
  for (int i = 0; i < 8; ++i) {
    float* dst = Xre + ((size_t)b * C_ + bm + tm + i) * N_ + bn + tn;
    *(float4*)(dst)     = make_float4(acc[i][0], acc[i][1], acc[i][2], acc[i][3]);
    *(float4*)(dst + 4) = make_float4(acc[i][4], acc[i][5], acc[i][6], acc[i][7]);
  }
}

// ---------------------------------------------------------------------------
// BN batch stats: stats[c] = sum, stats[C_+c] = sumsq over (b, n).
// grid = (C_, B_), block = 256. stats must be pre-zeroed.
// ---------------------------------------------------------------------------
__global__ __launch_bounds__(256) void bnstats(
    const float* __restrict__ Y, float* __restrict__ stats) {
  const int c = blockIdx.x, b = blockIdx.y;
  const float4* p = (const float4*)(Y + ((size_t)b * C_ + c) * N_);
  float s = 0.0f, s2 = 0.0f;
  for (int i = threadIdx.x; i < N_ / 4; i += 256) {
    float4 v = p[i];
    s  += v.x + v.y + v.z + v.w;
    s2 += v.x * v.x + v.y * v.y + v.z * v.z + v.w * v.w;
  }
#pragma unroll
  for (int off = 32; off; off >>= 1) {
    s  += __shfl_xor(s, off);
    s2 += __shfl_xor(s2, off);
  }
  __shared__ float ws[2][4];
  const int lane = threadIdx.x & 63, wid = threadIdx.x >> 6;
  if (lane == 0) { ws[0][wid] = s; ws[1][wid] = s2; }
  __syncthreads();
  if (threadIdx.x == 0) {
    float ts = ws[0][0] + ws[0][1] + ws[0][2] + ws[0][3];
    float t2 = ws[1][0] + ws[1][1] + ws[1][2] + ws[1][3];
    atomicAdd(&stats[c], ts);
    atomicAdd(&stats[C_ + c], t2);
  }
}

// ---------------------------------------------------------------------------
// BN apply + ReLU (+ optional residual). float4 grid-stride-free exact launch.
// o = relu(g*(y-mu)*rsqrt(var+eps)+beta) [+ x]
// grid = B_*C_*N_/(4*256) = 32768
// ---------------------------------------------------------------------------
__global__ __launch_bounds__(256) void bn_apply_res(
    const float* __restrict__ Y, const float* __restrict__ Xin,
    const float* __restrict__ stats, const float* __restrict__ g,
    const float* __restrict__ bta, float* __restrict__ Out) {
  const size_t i = ((size_t)blockIdx.x * 256 + threadIdx.x) * 4;
  const int c = (int)((i >> 12) & (C_ - 1));
  const float mu  = stats[c] * (1.0f / CNT_);
  const float var = stats[C_ + c] * (1.0f / CNT_) - mu * mu;
  const float rs  = rsqrtf(var + EPS_BN);
  const float ga = g[c], be = bta[c];
  float4 y = *(const float4*)(Y + i);
  float4 o;
  o.x = fmaxf(ga * (y.x - mu) * rs + be, 0.0f);
  o.y = fmaxf(ga * (y.y - mu) * rs + be, 0.0f);
  o.z = fmaxf(ga * (y.z - mu) * rs + be, 0.0f);
  o.w = fmaxf(ga * (y.w - mu) * rs + be, 0.0f);
  if (Xin) {
    float4 x = *(const float4*)(Xin + i);
    o.x += x.x; o.y += x.y; o.z += x.z; o.w += x.w;
  }
  *(float4*)(Out + i) = o;
}

// Zero the small stats region (colsum + stats2 + stats3 = 5120 floats)
__global__ __launch_bounds__(256) void zero_small(float* __restrict__ p) {
  p[blockIdx.x * 256 + threadIdx.x] = 0.0f;
}

// ---------------------------------------------------------------------------
extern "C" void kernel_launch(void* const* d_in, const int* in_sizes, int n_in,
                              void* d_out, int out_size, void* d_ws, size_t ws_size,
                              hipStream_t stream) {
  const float* x        = (const float*)d_in[0];
  const float* centers  = (const float*)d_in[1];
  const float* conv1_w  = (const float*)d_in[2];
  const float* conv1_b  = (const float*)d_in[3];
  const float* conv2_w  = (const float*)d_in[4];
  const float* bn2_g    = (const float*)d_in[5];
  const float* bn2_b    = (const float*)d_in[6];
  const float* conv3_w  = (const float*)d_in[7];
  const float* conv3_b  = (const float*)d_in[8];
  const float* bn3_g    = (const float*)d_in[9];
  const float* bn3_b    = (const float*)d_in[10];
  float* out = (float*)d_out;

  const size_t TENS = (size_t)B_ * C_ * N_;           // 33,554,432 floats
  float* buf1   = (float*)d_ws;                        // x1  -> y2 (conv2 out)
  float* buf2   = buf1 + TENS;                         // x_re -> t (bn2 out + res)
  float* att    = buf2 + TENS;                         // [B][N][M]
  float* colsum = att + (size_t)B_ * N_ * M_;          // 3072
  float* stats2 = colsum + B_ * M_;                    // 1024 (sum | sumsq)
  float* stats3 = stats2 + 2 * C_;                     // 1024

  // 1. zero colsum + stats (5120 floats, contiguous from colsum)
  zero_small<<<20, 256, 0, stream>>>(colsum);

  // 2. conv1: x1 = W1 @ x + b1
  gemm_wx<<<dim3(N_ / 128, C_ / 128, B_), 256, 0, stream>>>(conv1_w, x, buf1, conv1_b);

  // 3. att logits = x1^T @ centers
  gemm_att<<<dim3(N_ / 128, M_ / 64, B_), 256, 0, stream>>>(buf1, centers, att);

  // 4. softmax over k, in place
  softmax_rows<<<(B_ * N_) / 4, 256, 0, stream>>>(att);

  // 5. column sums over n
  colsum_kernel<<<dim3(16, B_), 256, 0, stream>>>(att, colsum);

  // 6. x_re = centers @ (att / (1e-6 + colsum))^T
  gemm_xre<<<dim3(N_ / 128, C_ / 128, B_), 256, 0, stream>>>(centers, att, colsum, buf2);

  // 7. conv2 (no bias): y2 = W2 @ x_re
  gemm_wx<<<dim3(N_ / 128, C_ / 128, B_), 256, 0, stream>>>(conv2_w, buf2, buf1, nullptr);

  // 8. BN2 stats
  bnstats<<<dim3(C_, B_), 256, 0, stream>>>(buf1, stats2);

  // 9. t = relu(bn2(y2)) + x
  bn_apply_res<<<(B_ * C_ * N_) / (4 * 256), 256, 0, stream>>>(buf1, x, stats2, bn2_g, bn2_b, buf2);

  // 10. conv3: z = W3 @ t + b3   (bias mathematically cancels in BN, kept for fidelity)
  gemm_wx<<<dim3(N_ / 128, C_ / 128, B_), 256, 0, stream>>>(conv3_w, buf2, out, conv3_b);

  // 11. BN3 stats
  bnstats<<<dim3(C_, B_), 256, 0, stream>>>(out, stats3);

  // 12. out = relu(bn3(z)), in place
  bn_apply_res<<<(B_ * C_ * N_) / (4 * 256), 256, 0, stream>>>(out, nullptr, stats3, bn3_g, bn3_b, out);
}

// Round 2
// 1186.275 us; speedup vs baseline: 1.5340x; 1.5340x over previous
//
#include <hip/hip_runtime.h>
#include <math.h>

// R1: conv GEMMs -> bf16 hi/lo split MFMA (3 passes: hh, hl, lh), fp32-grade
// accuracy. Activations for conv inputs stored as bf16 hi/lo planes in
// [n][c] (c-contiguous) layout; LDS in MFMA fragment order -> conflict-free
// ds_read_b128. att/xre/softmax/BN remain fp32 this round.

#define B_    16
#define C_    512      // CIN == COUT
#define N_    4096     // H*W
#define M_    192      // NSR*K codebook size
#define EPS_BN 1e-5f
#define CNT_  ((float)(B_ * N_))   // BN reduction count = 65536

typedef unsigned int   u32;
typedef unsigned short u16;
typedef short bf16x8 __attribute__((ext_vector_type(8)));
typedef float f32x4  __attribute__((ext_vector_type(4)));

// ---------------- bf16 split helpers (RNE) ----------------
__device__ __forceinline__ u16 bf16_rne(float f) {
  u32 u = __float_as_uint(f);
  u += 0x7FFFu + ((u >> 16) & 1u);
  return (u16)(u >> 16);
}
__device__ __forceinline__ float bf16_tof(u16 h) {
  return __uint_as_float(((u32)h) << 16);
}
// pack one value's (hi, lo) into one u32: hi | lo<<16
__device__ __forceinline__ u32 split_pack(float v) {
  u16 h = bf16_rne(v);
  u16 l = bf16_rne(v - bf16_tof(h));
  return (u32)h | ((u32)l << 16);
}
// two values -> packed hi-pair and lo-pair words
__device__ __forceinline__ void split2(float a, float b, u32& h, u32& l) {
  u16 ha = bf16_rne(a), hb = bf16_rne(b);
  u16 la = bf16_rne(a - bf16_tof(ha)), lb = bf16_rne(b - bf16_tof(hb));
  h = (u32)ha | ((u32)hb << 16);
  l = (u32)la | ((u32)lb << 16);
}

// ---------------------------------------------------------------------------
// Elementwise fp32 -> bf16 hi/lo planes (for the 512x512 weights). 256 blocks.
// ---------------------------------------------------------------------------
__global__ __launch_bounds__(256) void convert_ew(
    const float* __restrict__ s, u16* __restrict__ hi, u16* __restrict__ lo) {
  const int i = (blockIdx.x * 256 + threadIdx.x) * 4;
  float4 v = *(const float4*)(s + i);
  u32 ph0, pl0, ph1, pl1;
  split2(v.x, v.y, ph0, pl0);
  split2(v.z, v.w, ph1, pl1);
  uint2 H; H.x = ph0; H.y = ph1;
  uint2 L; L.x = pl0; L.y = pl1;
  *(uint2*)(hi + i) = H;
  *(uint2*)(lo + i) = L;
}

// ---------------------------------------------------------------------------
// x fp32 [b][c][n] -> xT hi/lo bf16 [b][n][c] via LDS 64x64 tile transpose.
// grid = (N_/64, C_/64, B_), block = 256
// ---------------------------------------------------------------------------
__global__ __launch_bounds__(256) void convert_x_T(
    const float* __restrict__ X, u16* __restrict__ Thi, u16* __restrict__ Tlo) {
  __shared__ u32 T[64][65];
  const int tid = threadIdx.x;
  const int n0 = blockIdx.x * 64, c0 = blockIdx.y * 64, b = blockIdx.z;
  const int cg = (tid & 15) * 4;
#pragma unroll
  for (int p = 0; p < 4; ++p) {
    const int r = p * 16 + (tid >> 4);
    float4 v = *(const float4*)(X + ((size_t)b * C_ + c0 + r) * N_ + n0 + cg);
    T[r][cg + 0] = split_pack(v.x);
    T[r][cg + 1] = split_pack(v.y);
    T[r][cg + 2] = split_pack(v.z);
    T[r][cg + 3] = split_pack(v.w);
  }
  __syncthreads();
#pragma unroll
  for (int it = 0; it < 2; ++it) {
    const int s = it * 256 + tid;
    const int nl = s >> 3, cb = s & 7;
    u32 u[8];
#pragma unroll
    for (int j = 0; j < 8; ++j) u[j] = T[cb * 8 + j][nl];
    uint4 H, L;
    H.x = (u[0] & 0xFFFFu) | (u[1] << 16);
    H.y = (u[2] & 0xFFFFu) | (u[3] << 16);
    H.z = (u[4] & 0xFFFFu) | (u[5] << 16);
    H.w = (u[6] & 0xFFFFu) | (u[7] << 16);
    L.x = (u[0] >> 16) | (u[1] & 0xFFFF0000u);
    L.y = (u[2] >> 16) | (u[3] & 0xFFFF0000u);
    L.z = (u[4] >> 16) | (u[5] & 0xFFFF0000u);
    L.w = (u[6] >> 16) | (u[7] & 0xFFFF0000u);
    const size_t o = ((size_t)b * N_ + n0 + nl) * C_ + c0 + cb * 8;
    *(uint4*)(Thi + o) = H;
    *(uint4*)(Tlo + o) = L;
  }
}

// ---------------------------------------------------------------------------
// Split-bf16 MFMA conv GEMM: Y[b][o][n] = sum_c W[o][c]*X[b][n][c] (+bias[o])
// A = W hi/lo [o][c]; B = XT hi/lo [n][c]; 128x128 tile, BK=32, 4 waves.
// LDS fragment-order slots: region(Ahi,Alo,Bhi,Blo) x [sub16][g][idx16] x 16B.
// grid = (N_/128, C_/128, B_), block = 256
// ---------------------------------------------------------------------------
__global__ __launch_bounds__(256) void conv_mfma(
    const u16* __restrict__ Whi, const u16* __restrict__ Wlo,
    const u16* __restrict__ Xhi, const u16* __restrict__ Xlo,
    float* __restrict__ Y, const float* __restrict__ bias) {
  __shared__ char sm[32768];
  const int tid = threadIdx.x, wid = tid >> 6, lane = tid & 63;
  const int bn = blockIdx.x * 128, bm = blockIdx.y * 128;
  const size_t boffX = (size_t)blockIdx.z * N_ * C_;
  const size_t boffY = (size_t)blockIdx.z * C_ * N_;

  // staging: 2048 slots of 16B (8 slots/thread). slot lin = it*4+wid:
  // region = lin>>3 (Ahi,Alo,Bhi,Blo), sub = lin&7 (16-row subtile),
  // per-lane: row16 = lane&15, kgroup g = lane>>4 -> 8 k-contig bf16.
  const u16* srcp[8];
  u32 ldsw[8];
#pragma unroll
  for (int it = 0; it < 8; ++it) {
    const int lin = it * 4 + wid, region = lin >> 3, sub = lin & 7;
    const u16* base = region == 0 ? Whi : region == 1 ? Wlo
                    : region == 2 ? (Xhi + boffX) : (Xlo + boffX);
    const int rowb = (region < 2 ? bm : bn) + sub * 16 + (lane & 15);
    srcp[it] = base + (size_t)rowb * C_ + (lane >> 4) * 8;
    ldsw[it] = (u32)(lin * 1024 + lane * 16);
  }

  f32x4 acc[4][4];
  const f32x4 zero = {0.f, 0.f, 0.f, 0.f};
#pragma unroll
  for (int i = 0; i < 4; ++i)
#pragma unroll
    for (int j = 0; j < 4; ++j) acc[i][j] = zero;

  const int arow = (wid >> 1) * 4, bcol = (wid & 1) * 4;
  const char* smL = sm + lane * 16;

  for (int k0 = 0; k0 < C_; k0 += 32) {
    float4 stg[8];
#pragma unroll
    for (int it = 0; it < 8; ++it) stg[it] = *(const float4*)(srcp[it] + k0);
#pragma unroll
    for (int it = 0; it < 8; ++it) *(float4*)(sm + ldsw[it]) = stg[it];
    __syncthreads();

    bf16x8 ah[4], al[4], bh[4], bl[4];
#pragma unroll
    for (int i = 0; i < 4; ++i) {
      ah[i] = *(const bf16x8*)(smL + (arow + i) * 1024);
      al[i] = *(const bf16x8*)(smL + 8192 + (arow + i) * 1024);
      bh[i] = *(const bf16x8*)(smL + 16384 + (bcol + i) * 1024);
      bl[i] = *(const bf16x8*)(smL + 24576 + (bcol + i) * 1024);
    }
#pragma unroll
    for (int i = 0; i < 4; ++i)
#pragma unroll
      for (int j = 0; j < 4; ++j) {
        acc[i][j] = __builtin_amdgcn_mfma_f32_16x16x32_bf16(ah[i], bh[j], acc[i][j], 0, 0, 0);
        acc[i][j] = __builtin_amdgcn_mfma_f32_16x16x32_bf16(ah[i], bl[j], acc[i][j], 0, 0, 0);
        acc[i][j] = __builtin_amdgcn_mfma_f32_16x16x32_bf16(al[i], bh[j], acc[i][j], 0, 0, 0);
      }
    __syncthreads();
  }

  // C/D layout (m89-verified): col = lane&15, row = (lane>>4)*4 + reg
  const int ro = (lane >> 4) * 4, co = lane & 15;
#pragma unroll
  for (int i = 0; i < 4; ++i) {
#pragma unroll
    for (int r = 0; r < 4; ++r) {
      const int o = bm + (wid >> 1) * 64 + i * 16 + ro + r;
      const float bv = bias ? bias[o] : 0.0f;
#pragma unroll
      for (int j = 0; j < 4; ++j) {
        const int n = bn + (wid & 1) * 64 + j * 16 + co;
        Y[boffY + (size_t)o * N_ + n] = acc[i][j][r] + bv;
      }
    }
  }
}

// ---------------------------------------------------------------------------
// Attention logits (fp32, unchanged): att[b][n][k] = sum_c x1[b][c][n]*cent[c][k]
// grid = (N_/128, M_/64, B_), block = 256
// ---------------------------------------------------------------------------
__global__ __launch_bounds__(256) void gemm_att(
    const float* __restrict__ X1, const float* __restrict__ Cent,
    float* __restrict__ Att) {
  const int tid = threadIdx.x;
  const int bn = blockIdx.x * 128;
  const int bk = blockIdx.y * 64;
  const float* Xb = X1 + (size_t)blockIdx.z * C_ * N_;

  __shared__ float As[8][128];
  __shared__ float Bs[8][64];

  float acc[8][4];
#pragma unroll
  for (int i = 0; i < 8; ++i)
#pragma unroll
    for (int j = 0; j < 4; ++j) acc[i][j] = 0.0f;

  const int tm = (tid >> 4) << 3;
  const int tn = (tid & 15) << 2;
  const int a_kc = tid >> 5;
  const int a_m4 = (tid & 31) << 2;
  const int b_kc = tid >> 5;
  const int b_c2 = (tid & 31) << 1;

  for (int k0 = 0; k0 < C_; k0 += 8) {
    *(float4*)&As[a_kc][a_m4] =
        *(const float4*)(Xb + (size_t)(k0 + a_kc) * N_ + bn + a_m4);
    *(float2*)&Bs[b_kc][b_c2] =
        *(const float2*)(Cent + (size_t)(k0 + b_kc) * M_ + bk + b_c2);
    __syncthreads();
#pragma unroll
    for (int kk = 0; kk < 8; ++kk) {
      float ar[8], br[4];
#pragma unroll
      for (int i = 0; i < 8; ++i) ar[i] = As[kk][tm + i];
#pragma unroll
      for (int j = 0; j < 4; ++j) br[j] = Bs[kk][tn + j];
#pragma unroll
      for (int i = 0; i < 8; ++i)
#pragma unroll
        for (int j = 0; j < 4; ++j) acc[i][j] = fmaf(ar[i], br[j], acc[i][j]);
    }
    __syncthreads();
  }

#pragma unroll
  for (int i = 0; i < 8; ++i) {
    float4 o = make_float4(acc[i][0], acc[i][1], acc[i][2], acc[i][3]);
    *(float4*)(Att + ((size_t)blockIdx.z * N_ + bn + tm + i) * M_ + bk + tn) = o;
  }
}

// ---------------------------------------------------------------------------
// Row softmax over k (192), in place. One wave per row. grid = B_*N_/4
// ---------------------------------------------------------------------------
__global__ __launch_bounds__(256) void softmax_rows(float* __restrict__ Att) {
  const int wid  = threadIdx.x >> 6;
  const int lane = threadIdx.x & 63;
  const size_t row = (size_t)blockIdx.x * 4 + wid;
  float* p = Att + row * M_;
  float v0 = p[lane], v1 = p[lane + 64], v2 = p[lane + 128];
  float m = fmaxf(v0, fmaxf(v1, v2));
#pragma unroll
  for (int off = 32; off; off >>= 1) m = fmaxf(m, __shfl_xor(m, off));
  v0 = __expf(v0 - m);
  v1 = __expf(v1 - m);
  v2 = __expf(v2 - m);
  float s = v0 + v1 + v2;
#pragma unroll
  for (int off = 32; off; off >>= 1) s += __shfl_xor(s, off);
  const float r = 1.0f / s;
  p[lane]       = v0 * r;
  p[lane + 64]  = v1 * r;
  p[lane + 128] = v2 * r;
}

// ---------------------------------------------------------------------------
// Column sums over n: Cs[b][k] = sum_n att[b][n][k]. grid = (16, B_)
// ---------------------------------------------------------------------------
__global__ __launch_bounds__(256) void colsum_kernel(
    const float* __restrict__ Att, float* __restrict__ Cs) {
  const int b  = blockIdx.y;
  const int n0 = blockIdx.x * 256;
  const int k  = threadIdx.x;
  if (k < M_) {
    float s = 0.0f;
    const float* p = Att + ((size_t)b * N_ + n0) * M_ + k;
    for (int n = 0; n < 256; ++n) s += p[(size_t)n * M_];
    atomicAdd(&Cs[b * M_ + k], s);
  }
}

// ---------------------------------------------------------------------------
// Reconstruction (fp32 compute, split-bf16 transposed output):
//   xreT[b][n][c] (hi/lo) = sum_k cent[c][k] * att[b][n][k]/(1e-6+Cs[b][k])
// grid = (N_/128, C_/128, B_), block = 256
// ---------------------------------------------------------------------------
__global__ __launch_bounds__(256) void gemm_xre(
    const float* __restrict__ Cent, const float* __restrict__ Att,
    const float* __restrict__ Cs, u16* __restrict__ XThi, u16* __restrict__ XTlo) {
  const int tid = threadIdx.x;
  const int bn = blockIdx.x * 128;   // n
  const int bm = blockIdx.y * 128;   // c
  const int b  = blockIdx.z;

  __shared__ float As[8][128];   // [k][c]
  __shared__ float Bs[8][128];   // [k][n]
  __shared__ float inv[M_];

  if (tid < M_) inv[tid] = 1.0f / (1e-6f + Cs[b * M_ + tid]);
  __syncthreads();

  float acc[8][8];
#pragma unroll
  for (int i = 0; i < 8; ++i)
#pragma unroll
    for (int j = 0; j < 8; ++j) acc[i][j] = 0.0f;

  const int tm = (tid >> 4) << 3;     // c
  const int tn = (tid & 15) << 3;     // n
  const int a_row = tid >> 1;
  const int a_col = (tid & 1) << 2;
  const int b_row = tid >> 1;
  const int b_col = (tid & 1) << 2;

  for (int k0 = 0; k0 < M_; k0 += 8) {
    float4 av = *(const float4*)(Cent + (size_t)(bm + a_row) * M_ + k0 + a_col);
    As[a_col + 0][a_row] = av.x;
    As[a_col + 1][a_row] = av.y;
    As[a_col + 2][a_row] = av.z;
    As[a_col + 3][a_row] = av.w;
    float4 bv = *(const float4*)(Att + ((size_t)b * N_ + bn + b_row) * M_ + k0 + b_col);
    Bs[b_col + 0][b_row] = bv.x * inv[k0 + b_col + 0];
    Bs[b_col + 1][b_row] = bv.y * inv[k0 + b_col + 1];
    Bs[b_col + 2][b_row] = bv.z * inv[k0 + b_col + 2];
    Bs[b_col + 3][b_row] = bv.w * inv[k0 + b_col + 3];
    __syncthreads();
#pragma unroll
    for (int kk = 0; kk < 8; ++kk) {
      float ar[8], br[8];
#pragma unroll
      for (int i = 0; i < 8; ++i) ar[i] = As[kk][tm + i];
#pragma unroll
      for (int j = 0; j < 8; ++j) br[j] = Bs[kk][tn + j];
#pragma unroll
      for (int i = 0; i < 8; ++i)
#pragma unroll
        for (int j = 0; j < 8; ++j) acc[i][j] = fmaf(ar[i], br[j], acc[i][j]);
    }
    __syncthreads();
  }

  // write transposed split planes: 8 c-contig values per n-row -> 16B stores
#pragma unroll
  for (int jj = 0; jj < 8; ++jj) {
    uint4 H, L;
    split2(acc[0][jj], acc[1][jj], H.x, L.x);
    split2(acc[2][jj], acc[3][jj], H.y, L.y);
    split2(acc[4][jj], acc[5][jj], H.z, L.z);
    split2(acc[6][jj], acc[7][jj], H.w, L.w);
    const size_t o = ((size_t)b * N_ + bn + tn + jj) * C_ + bm + tm;
    *(uint4*)(XThi + o) = H;
    *(uint4*)(XTlo + o) = L;
  }
}

// ---------------------------------------------------------------------------
// BN batch stats: stats[c] = sum, stats[C_+c] = sumsq. grid = (C_, B_).
// ---------------------------------------------------------------------------
__global__ __launch_bounds__(256) void bnstats(
    const float* __restrict__ Y, float* __restrict__ stats) {
  const int c = blockIdx.x, b = blockIdx.y;
  const float4* p = (const float4*)(Y + ((size_t)b * C_ + c) * N_);
  float s = 0.0f, s2 = 0.0f;
  for (int i = threadIdx.x; i < N_ / 4; i += 256) {
    float4 v = p[i];
    s  += v.x + v.y + v.z + v.w;
    s2 += v.x * v.x + v.y * v.y + v.z * v.z + v.w * v.w;
  }
#pragma unroll
  for (int off = 32; off; off >>= 1) {
    s  += __shfl_xor(s, off);
    s2 += __shfl_xor(s2, off);
  }
  __shared__ float ws[2][4];
  const int lane = threadIdx.x & 63, wid = threadIdx.x >> 6;
  if (lane == 0) { ws[0][wid] = s; ws[1][wid] = s2; }
  __syncthreads();
  if (threadIdx.x == 0) {
    float ts = ws[0][0] + ws[0][1] + ws[0][2] + ws[0][3];
    float t2 = ws[1][0] + ws[1][1] + ws[1][2] + ws[1][3];
    atomicAdd(&stats[c], ts);
    atomicAdd(&stats[C_ + c], t2);
  }
}

// ---------------------------------------------------------------------------
// BN2 apply + ReLU + residual, with transpose to split-bf16 [n][c] planes:
//   tT[b][n][c] = relu(bn2(y2))[c][n] + x[c][n]
// grid = (N_/64, C_/64, B_), block = 256 (LDS 64x64 tile)
// ---------------------------------------------------------------------------
__global__ __launch_bounds__(256) void bn_res_T(
    const float* __restrict__ Y, const float* __restrict__ X,
    const float* __restrict__ stats, const float* __restrict__ g,
    const float* __restrict__ bta,
    u16* __restrict__ Thi, u16* __restrict__ Tlo) {
  __shared__ u32 T[64][65];
  const int tid = threadIdx.x;
  const int n0 = blockIdx.x * 64, c0 = blockIdx.y * 64, b = blockIdx.z;
  const int cg = (tid & 15) * 4;
#pragma unroll
  for (int p = 0; p < 4; ++p) {
    const int r = p * 16 + (tid >> 4);
    const int c = c0 + r;
    const float mu  = stats[c] * (1.0f / CNT_);
    const float var = stats[C_ + c] * (1.0f / CNT_) - mu * mu;
    const float rs  = rsqrtf(var + EPS_BN);
    const float ga = g[c], be = bta[c];
    const size_t idx = ((size_t)b * C_ + c) * N_ + n0 + cg;
    float4 v  = *(const float4*)(Y + idx);
    float4 xv = *(const float4*)(X + idx);
    float4 t;
    t.x = fmaxf(ga * (v.x - mu) * rs + be, 0.0f) + xv.x;
    t.y = fmaxf(ga * (v.y - mu) * rs + be, 0.0f) + xv.y;
    t.z = fmaxf(ga * (v.z - mu) * rs + be, 0.0f) + xv.z;
    t.w = fmaxf(ga * (v.w - mu) * rs + be, 0.0f) + xv.w;
    T[r][cg + 0] = split_pack(t.x);
    T[r][cg + 1] = split_pack(t.y);
    T[r][cg + 2] = split_pack(t.z);
    T[r][cg + 3] = split_pack(t.w);
  }
  __syncthreads();
#pragma unroll
  for (int it = 0; it < 2; ++it) {
    const int s = it * 256 + tid;
    const int nl = s >> 3, cb = s & 7;
    u32 u[8];
#pragma unroll
    for (int j = 0; j < 8; ++j) u[j] = T[cb * 8 + j][nl];
    uint4 H, L;
    H.x = (u[0] & 0xFFFFu) | (u[1] << 16);
    H.y = (u[2] & 0xFFFFu) | (u[3] << 16);
    H.z = (u[4] & 0xFFFFu) | (u[5] << 16);
    H.w = (u[6] & 0xFFFFu) | (u[7] << 16);
    L.x = (u[0] >> 16) | (u[1] & 0xFFFF0000u);
    L.y = (u[2] >> 16) | (u[3] & 0xFFFF0000u);
    L.z = (u[4] >> 16) | (u[5] & 0xFFFF0000u);
    L.w = (u[6] >> 16) | (u[7] & 0xFFFF0000u);
    const size_t o = ((size_t)b * N_ + n0 + nl) * C_ + c0 + cb * 8;
    *(uint4*)(Thi + o) = H;
    *(uint4*)(Tlo + o) = L;
  }
}

// ---------------------------------------------------------------------------
// Final BN apply + ReLU (in place on d_out). grid = B_*C_*N_/(4*256)
// ---------------------------------------------------------------------------
__global__ __launch_bounds__(256) void bn_apply(
    const float* __restrict__ Y, const float* __restrict__ stats,
    const float* __restrict__ g, const float* __restrict__ bta,
    float* __restrict__ Out) {
  const size_t i = ((size_t)blockIdx.x * 256 + threadIdx.x) * 4;
  const int c = (int)((i >> 12) & (C_ - 1));
  const float mu  = stats[c] * (1.0f / CNT_);
  const float var = stats[C_ + c] * (1.0f / CNT_) - mu * mu;
  const float rs  = rsqrtf(var + EPS_BN);
  const float ga = g[c], be = bta[c];
  float4 y = *(const float4*)(Y + i);
  float4 o;
  o.x = fmaxf(ga * (y.x - mu) * rs + be, 0.0f);
  o.y = fmaxf(ga * (y.y - mu) * rs + be, 0.0f);
  o.z = fmaxf(ga * (y.z - mu) * rs + be, 0.0f);
  o.w = fmaxf(ga * (y.w - mu) * rs + be, 0.0f);
  *(float4*)(Out + i) = o;
}

// Zero the small stats region (colsum + stats2 + stats3 = 5120 floats)
__global__ __launch_bounds__(256) void zero_small(float* __restrict__ p) {
  p[blockIdx.x * 256 + threadIdx.x] = 0.0f;
}

// ---------------------------------------------------------------------------
extern "C" void kernel_launch(void* const* d_in, const int* in_sizes, int n_in,
                              void* d_out, int out_size, void* d_ws, size_t ws_size,
                              hipStream_t stream) {
  const float* x        = (const float*)d_in[0];
  const float* centers  = (const float*)d_in[1];
  const float* conv1_w  = (const float*)d_in[2];
  const float* conv1_b  = (const float*)d_in[3];
  const float* conv2_w  = (const float*)d_in[4];
  const float* bn2_g    = (const float*)d_in[5];
  const float* bn2_b    = (const float*)d_in[6];
  const float* conv3_w  = (const float*)d_in[7];
  const float* conv3_b  = (const float*)d_in[8];
  const float* bn3_g    = (const float*)d_in[9];
  const float* bn3_b    = (const float*)d_in[10];
  float* out = (float*)d_out;

  const size_t TENS = (size_t)B_ * C_ * N_;       // 33,554,432 elems
  char* w = (char*)d_ws;
  // region A (134 MB): xT planes -> xreT planes -> tT planes
  u16* xThi = (u16*)w;
  u16* xTlo = xThi + TENS;
  // region B (134 MB): x1 -> y2
  float* x1 = (float*)(w + 134217728);
  // region C (50.3 MB): att
  float* att = (float*)(w + 268435456);
  // small region
  float* colsum = (float*)(w + 268435456 + 50331648);  // 3072
  float* stats2 = colsum + B_ * M_;                    // 1024
  float* stats3 = stats2 + 2 * C_;                     // 1024
  // weight planes (3 MB)
  u16* w1hi = (u16*)(stats3 + 2 * C_);
  u16* w1lo = w1hi + 262144;
  u16* w2hi = w1lo + 262144;
  u16* w2lo = w2hi + 262144;
  u16* w3hi = w2lo + 262144;
  u16* w3lo = w3hi + 262144;
  // aliases
  u16* xreThi = xThi;  u16* xreTlo = xTlo;
  u16* tThi   = xThi;  u16* tTlo   = xTlo;
  float* y2 = x1;

  // 1. zero colsum+stats
  zero_small<<<20, 256, 0, stream>>>(colsum);
  // 2. weight hi/lo planes
  convert_ew<<<256, 256, 0, stream>>>(conv1_w, w1hi, w1lo);
  convert_ew<<<256, 256, 0, stream>>>(conv2_w, w2hi, w2lo);
  convert_ew<<<256, 256, 0, stream>>>(conv3_w, w3hi, w3lo);
  // 3. x -> xT hi/lo [n][c]
  convert_x_T<<<dim3(N_ / 64, C_ / 64, B_), 256, 0, stream>>>(x, xThi, xTlo);
  // 4. conv1 (MFMA split): x1[o][n] = W1 @ x + b1
  conv_mfma<<<dim3(N_ / 128, C_ / 128, B_), 256, 0, stream>>>(
      w1hi, w1lo, xThi, xTlo, x1, conv1_b);
  // 5. att logits
  gemm_att<<<dim3(N_ / 128, M_ / 64, B_), 256, 0, stream>>>(x1, centers, att);
  // 6. softmax
  softmax_rows<<<(B_ * N_) / 4, 256, 0, stream>>>(att);
  // 7. column sums
  colsum_kernel<<<dim3(16, B_), 256, 0, stream>>>(att, colsum);
  // 8. xreT hi/lo [n][c] = centers @ (att/colsum)^T
  gemm_xre<<<dim3(N_ / 128, C_ / 128, B_), 256, 0, stream>>>(
      centers, att, colsum, xreThi, xreTlo);
  // 9. conv2 (MFMA split): y2 = W2 @ xre
  conv_mfma<<<dim3(N_ / 128, C_ / 128, B_), 256, 0, stream>>>(
      w2hi, w2lo, xreThi, xreTlo, y2, nullptr);
  // 10. BN2 stats
  bnstats<<<dim3(C_, B_), 256, 0, stream>>>(y2, stats2);
  // 11. tT hi/lo [n][c] = relu(bn2(y2)) + x
  bn_res_T<<<dim3(N_ / 64, C_ / 64, B_), 256, 0, stream>>>(
      y2, x, stats2, bn2_g, bn2_b, tThi, tTlo);
  // 12. conv3 (MFMA split): out = W3 @ t + b3
  conv_mfma<<<dim3(N_ / 128, C_ / 128, B_), 256, 0, stream>>>(
      w3hi, w3lo, tThi, tTlo, out, conv3_b);
  // 13. BN3 stats
  bnstats<<<dim3(C_, B_), 256, 0, stream>>>(out, stats3);
  // 14. out = relu(bn3(out)), in place
  bn_apply<<<(B_ * C_ * N_) / (4 * 256), 256, 0, stream>>>(
      out, stats3, bn3_g, bn3_b, out);
}

// Round 4
// 1119.569 us; speedup vs baseline: 1.6254x; 1.0596x over previous
//
#include <hip/hip_runtime.h>
#include <math.h>

// R3 (resubmit; R3 bench never acquired a GPU): everything matmul-shaped on
// matrix cores with split-bf16 (hi/lo, 3-pass) fp32-grade accuracy. Fused att
// GEMM + softmax + colsum-atomics. xre GEMM via per-batch inv-colsum-scaled
// centers. conv1/xre emit split planes directly.

#define B_    16
#define C_    512      // CIN == COUT
#define N_    4096     // H*W
#define M_    192      // NSR*K codebook size
#define EPS_BN 1e-5f
#define CNT_  ((float)(B_ * N_))   // BN reduction count = 65536

typedef unsigned int   u32;
typedef unsigned short u16;
typedef short bf16x8 __attribute__((ext_vector_type(8)));
typedef float f32x4  __attribute__((ext_vector_type(4)));

// ---------------- bf16 split helpers (RNE) ----------------
__device__ __forceinline__ u16 bf16_rne(float f) {
  u32 u = __float_as_uint(f);
  u += 0x7FFFu + ((u >> 16) & 1u);
  return (u16)(u >> 16);
}
__device__ __forceinline__ float bf16_tof(u16 h) {
  return __uint_as_float(((u32)h) << 16);
}
__device__ __forceinline__ u32 split_pack(float v) {
  u16 h = bf16_rne(v);
  u16 l = bf16_rne(v - bf16_tof(h));
  return (u32)h | ((u32)l << 16);
}
__device__ __forceinline__ void split2(float a, float b, u32& h, u32& l) {
  u16 ha = bf16_rne(a), hb = bf16_rne(b);
  u16 la = bf16_rne(a - bf16_tof(ha)), lb = bf16_rne(b - bf16_tof(hb));
  h = (u32)ha | ((u32)hb << 16);
  l = (u32)la | ((u32)lb << 16);
}

// ---------------------------------------------------------------------------
// Elementwise fp32 -> bf16 hi/lo planes (512x512 weights). grid 256.
// ---------------------------------------------------------------------------
__global__ __launch_bounds__(256) void convert_ew(
    const float* __restrict__ s, u16* __restrict__ hi, u16* __restrict__ lo) {
  const int i = (blockIdx.x * 256 + threadIdx.x) * 4;
  float4 v = *(const float4*)(s + i);
  u32 ph0, pl0, ph1, pl1;
  split2(v.x, v.y, ph0, pl0);
  split2(v.z, v.w, ph1, pl1);
  uint2 H; H.x = ph0; H.y = ph1;
  uint2 L; L.x = pl0; L.y = pl1;
  *(uint2*)(hi + i) = H;
  *(uint2*)(lo + i) = L;
}

// ---------------------------------------------------------------------------
// centers fp32 [c][k] -> centT hi/lo [k][c]. 98304 elems, grid 384.
// ---------------------------------------------------------------------------
__global__ __launch_bounds__(256) void centT_conv(
    const float* __restrict__ cent, u16* __restrict__ hi, u16* __restrict__ lo) {
  const int idx = blockIdx.x * 256 + threadIdx.x;   // idx = k*512 + c
  const int k = idx >> 9, c = idx & 511;
  const float v = cent[c * M_ + k];
  u16 h = bf16_rne(v);
  u16 l = bf16_rne(v - bf16_tof(h));
  hi[idx] = h;
  lo[idx] = l;
}

// ---------------------------------------------------------------------------
// cent_scaled[b][c][k] = centers[c][k] / (1e-6 + colsum[b][k]), split hi/lo.
// grid = (384, B_)
// ---------------------------------------------------------------------------
__global__ __launch_bounds__(256) void cent_scale(
    const float* __restrict__ cent, const float* __restrict__ colsum,
    u16* __restrict__ hi, u16* __restrict__ lo) {
  const int idx = blockIdx.x * 256 + threadIdx.x;   // c*192 + k
  const int b = blockIdx.y;
  const int c = idx / M_;
  const int k = idx - c * M_;
  const float v = cent[idx] / (1e-6f + colsum[b * M_ + k]);
  u16 h = bf16_rne(v);
  u16 l = bf16_rne(v - bf16_tof(h));
  const size_t o = (size_t)b * C_ * M_ + idx;
  hi[o] = h;
  lo[o] = l;
}

// ---------------------------------------------------------------------------
// x fp32 [b][c][n] -> xT hi/lo bf16 [b][n][c] via LDS 64x64 transpose.
// grid = (N_/64, C_/64, B_)
// ---------------------------------------------------------------------------
__global__ __launch_bounds__(256) void convert_x_T(
    const float* __restrict__ X, u16* __restrict__ Thi, u16* __restrict__ Tlo) {
  __shared__ u32 T[64][65];
  const int tid = threadIdx.x;
  const int n0 = blockIdx.x * 64, c0 = blockIdx.y * 64, b = blockIdx.z;
  const int cg = (tid & 15) * 4;
#pragma unroll
  for (int p = 0; p < 4; ++p) {
    const int r = p * 16 + (tid >> 4);
    float4 v = *(const float4*)(X + ((size_t)b * C_ + c0 + r) * N_ + n0 + cg);
    T[r][cg + 0] = split_pack(v.x);
    T[r][cg + 1] = split_pack(v.y);
    T[r][cg + 2] = split_pack(v.z);
    T[r][cg + 3] = split_pack(v.w);
  }
  __syncthreads();
#pragma unroll
  for (int it = 0; it < 2; ++it) {
    const int s = it * 256 + tid;
    const int nl = s >> 3, cb = s & 7;
    u32 u[8];
#pragma unroll
    for (int j = 0; j < 8; ++j) u[j] = T[cb * 8 + j][nl];
    uint4 H, L;
    H.x = (u[0] & 0xFFFFu) | (u[1] << 16);
    H.y = (u[2] & 0xFFFFu) | (u[3] << 16);
    H.z = (u[4] & 0xFFFFu) | (u[5] << 16);
    H.w = (u[6] & 0xFFFFu) | (u[7] << 16);
    L.x = (u[0] >> 16) | (u[1] & 0xFFFF0000u);
    L.y = (u[2] >> 16) | (u[3] & 0xFFFF0000u);
    L.z = (u[4] >> 16) | (u[5] & 0xFFFF0000u);
    L.w = (u[6] >> 16) | (u[7] & 0xFFFF0000u);
    const size_t o = ((size_t)b * N_ + n0 + nl) * C_ + c0 + cb * 8;
    *(uint4*)(Thi + o) = H;
    *(uint4*)(Tlo + o) = L;
  }
}

// ---------------------------------------------------------------------------
// Split-bf16 MFMA GEMM template. D[row][col] = sum_k A[row][k]*B[col][k].
//   A hi/lo: [rowA][KD] (per-batch if APB), B hi/lo: [b][rowB=n][KD].
//   OMODE 0: Y fp32 [b][row][N_] (+bias). OMODE 1: planes [b][col][C_] (+bias).
// 128x128 tile, BK=32, 4 waves. grid = (N_/128, C_/128, B_)
// ---------------------------------------------------------------------------
template <int KD, int OMODE, bool APB>
__global__ __launch_bounds__(256) void mm_mfma(
    const u16* __restrict__ Ahi, const u16* __restrict__ Alo,
    const u16* __restrict__ Bhi, const u16* __restrict__ Blo,
    float* __restrict__ Yf, u16* __restrict__ Phi, u16* __restrict__ Plo,
    const float* __restrict__ bias) {
  __shared__ char sm[32768];
  const int tid = threadIdx.x, wid = tid >> 6, lane = tid & 63;
  const int bn = blockIdx.x * 128, bm = blockIdx.y * 128;
  const size_t boffB = (size_t)blockIdx.z * N_ * KD;
  const size_t aoff = APB ? (size_t)blockIdx.z * C_ * KD : 0;

  const u16* srcp[8];
  u32 ldsw[8];
#pragma unroll
  for (int it = 0; it < 8; ++it) {
    const int lin = it * 4 + wid, region = lin >> 3, sub = lin & 7;
    const u16* base = region == 0 ? (Ahi + aoff) : region == 1 ? (Alo + aoff)
                    : region == 2 ? (Bhi + boffB) : (Blo + boffB);
    const int rowb = (region < 2 ? bm : bn) + sub * 16 + (lane & 15);
    srcp[it] = base + (size_t)rowb * KD + (lane >> 4) * 8;
    ldsw[it] = (u32)(lin * 1024 + lane * 16);
  }

  f32x4 acc[4][4];
  const f32x4 zero = {0.f, 0.f, 0.f, 0.f};
#pragma unroll
  for (int i = 0; i < 4; ++i)
#pragma unroll
    for (int j = 0; j < 4; ++j) acc[i][j] = zero;

  const int arow = (wid >> 1) * 4, bcol = (wid & 1) * 4;
  const char* smL = sm + lane * 16;

  for (int k0 = 0; k0 < KD; k0 += 32) {
    float4 stg[8];
#pragma unroll
    for (int it = 0; it < 8; ++it) stg[it] = *(const float4*)(srcp[it] + k0);
#pragma unroll
    for (int it = 0; it < 8; ++it) *(float4*)(sm + ldsw[it]) = stg[it];
    __syncthreads();

    bf16x8 ah[4], al[4], bh[4], bl[4];
#pragma unroll
    for (int i = 0; i < 4; ++i) {
      ah[i] = *(const bf16x8*)(smL + (arow + i) * 1024);
      al[i] = *(const bf16x8*)(smL + 8192 + (arow + i) * 1024);
      bh[i] = *(const bf16x8*)(smL + 16384 + (bcol + i) * 1024);
      bl[i] = *(const bf16x8*)(smL + 24576 + (bcol + i) * 1024);
    }
#pragma unroll
    for (int i = 0; i < 4; ++i)
#pragma unroll
      for (int j = 0; j < 4; ++j) {
        acc[i][j] = __builtin_amdgcn_mfma_f32_16x16x32_bf16(ah[i], bh[j], acc[i][j], 0, 0, 0);
        acc[i][j] = __builtin_amdgcn_mfma_f32_16x16x32_bf16(ah[i], bl[j], acc[i][j], 0, 0, 0);
        acc[i][j] = __builtin_amdgcn_mfma_f32_16x16x32_bf16(al[i], bh[j], acc[i][j], 0, 0, 0);
      }
    __syncthreads();
  }

  // C/D layout (m89-verified): col = lane&15, row = (lane>>4)*4 + reg
  const int ro = (lane >> 4) * 4, co = lane & 15;
  if (OMODE == 0) {
    const size_t boffY = (size_t)blockIdx.z * C_ * N_;
#pragma unroll
    for (int i = 0; i < 4; ++i) {
#pragma unroll
      for (int r = 0; r < 4; ++r) {
        const int o = bm + (wid >> 1) * 64 + i * 16 + ro + r;
        const float bv = bias ? bias[o] : 0.0f;
#pragma unroll
        for (int j = 0; j < 4; ++j) {
          const int n = bn + (wid & 1) * 64 + j * 16 + co;
          Yf[boffY + (size_t)o * N_ + n] = acc[i][j][r] + bv;
        }
      }
    }
  } else {
    // planes [b][n][row], row-dim width = C_; lane holds 4 consecutive rows
#pragma unroll
    for (int i = 0; i < 4; ++i) {
      const int ob = bm + (wid >> 1) * 64 + i * 16 + ro;
      float bv[4];
#pragma unroll
      for (int r = 0; r < 4; ++r) bv[r] = bias ? bias[ob + r] : 0.0f;
#pragma unroll
      for (int j = 0; j < 4; ++j) {
        const int n = bn + (wid & 1) * 64 + j * 16 + co;
        u32 h0, l0, h1, l1;
        split2(acc[i][j][0] + bv[0], acc[i][j][1] + bv[1], h0, l0);
        split2(acc[i][j][2] + bv[2], acc[i][j][3] + bv[3], h1, l1);
        const size_t o = ((size_t)blockIdx.z * N_ + n) * C_ + ob;
        uint2 H; H.x = h0; H.y = h1;
        uint2 L; L.x = l0; L.y = l1;
        *(uint2*)(Phi + o) = H;
        *(uint2*)(Plo + o) = L;
      }
    }
  }
}

// ---------------------------------------------------------------------------
// Fused attention: logits (MFMA, split-bf16) + softmax + colsum atomics.
//   D[k][n] = sum_c centT[k][c] * x1T[b][n][c];  e = softmax_k(D)
//   writes e hi/lo planes [b][n][k]; colsum[b][k] += sum_n e.
// Block: 256 thr, 4 waves; tile n=128 (wave: 2 n-subtiles), k=192 (12 tiles).
// LDS 40KB: A_hi[12] A_lo[12] B_hi[8] B_lo[8] subtiles of 1KB.
// grid = (N_/128, 1, B_)
// ---------------------------------------------------------------------------
__global__ __launch_bounds__(256) void att_mfma(
    const u16* __restrict__ CThi, const u16* __restrict__ CTlo,
    const u16* __restrict__ Xhi, const u16* __restrict__ Xlo,
    u16* __restrict__ Ehi, u16* __restrict__ Elo,
    float* __restrict__ colsum) {
  __shared__ char sm[40960];
  const int tid = threadIdx.x, wid = tid >> 6, lane = tid & 63;
  const int bn = blockIdx.x * 128;
  const int b = blockIdx.z;
  const size_t bX = (size_t)b * N_ * C_;

  const u16* srcp[10];
  u32 ldsw[10];
#pragma unroll
  for (int it = 0; it < 10; ++it) {
    const int lin = it * 4 + wid;
    const u16* base;
    int rowb;
    if (lin < 12)      { base = CThi;      rowb = lin * 16 + (lane & 15); }
    else if (lin < 24) { base = CTlo;      rowb = (lin - 12) * 16 + (lane & 15); }
    else if (lin < 32) { base = Xhi + bX;  rowb = bn + (lin - 24) * 16 + (lane & 15); }
    else               { base = Xlo + bX;  rowb = bn + (lin - 32) * 16 + (lane & 15); }
    srcp[it] = base + (size_t)rowb * C_ + (lane >> 4) * 8;
    ldsw[it] = (u32)(lin * 1024 + lane * 16);
  }

  f32x4 acc[12][2];
  const f32x4 zero = {0.f, 0.f, 0.f, 0.f};
#pragma unroll
  for (int i = 0; i < 12; ++i) {
    acc[i][0] = zero;
    acc[i][1] = zero;
  }

  const char* smL = sm + lane * 16;

  for (int k0 = 0; k0 < C_; k0 += 32) {
    float4 stg[10];
#pragma unroll
    for (int it = 0; it < 10; ++it) stg[it] = *(const float4*)(srcp[it] + k0);
#pragma unroll
    for (int it = 0; it < 10; ++it) *(float4*)(sm + ldsw[it]) = stg[it];
    __syncthreads();

    bf16x8 bh[2], bl[2];
#pragma unroll
    for (int jj = 0; jj < 2; ++jj) {
      bh[jj] = *(const bf16x8*)(smL + (24 + wid * 2 + jj) * 1024);
      bl[jj] = *(const bf16x8*)(smL + (32 + wid * 2 + jj) * 1024);
    }
#pragma unroll
    for (int i = 0; i < 12; ++i) {
      bf16x8 ah = *(const bf16x8*)(smL + i * 1024);
      bf16x8 al = *(const bf16x8*)(smL + (12 + i) * 1024);
#pragma unroll
      for (int jj = 0; jj < 2; ++jj) {
        acc[i][jj] = __builtin_amdgcn_mfma_f32_16x16x32_bf16(ah, bh[jj], acc[i][jj], 0, 0, 0);
        acc[i][jj] = __builtin_amdgcn_mfma_f32_16x16x32_bf16(ah, bl[jj], acc[i][jj], 0, 0, 0);
        acc[i][jj] = __builtin_amdgcn_mfma_f32_16x16x32_bf16(al, bh[jj], acc[i][jj], 0, 0, 0);
      }
    }
    __syncthreads();
  }

  // epilogue: k = i*16 + (lane>>4)*4 + r ; n = bn + (wid*2+jj)*16 + (lane&15)
  const int ro = (lane >> 4) * 4;
#pragma unroll
  for (int jj = 0; jj < 2; ++jj) {
    const int nn = bn + (wid * 2 + jj) * 16 + (lane & 15);
    float mx = acc[0][jj][0];
#pragma unroll
    for (int i = 0; i < 12; ++i)
#pragma unroll
      for (int r = 0; r < 4; ++r) mx = fmaxf(mx, acc[i][jj][r]);
    mx = fmaxf(mx, __shfl_xor(mx, 16));
    mx = fmaxf(mx, __shfl_xor(mx, 32));
    float s = 0.0f;
#pragma unroll
    for (int i = 0; i < 12; ++i)
#pragma unroll
      for (int r = 0; r < 4; ++r) {
        const float e = __expf(acc[i][jj][r] - mx);
        acc[i][jj][r] = e;
        s += e;
      }
    s += __shfl_xor(s, 16);
    s += __shfl_xor(s, 32);
    const float rinv = 1.0f / s;
    const size_t rowo = ((size_t)b * N_ + nn) * M_;
#pragma unroll
    for (int i = 0; i < 12; ++i) {
      float v[4];
#pragma unroll
      for (int r = 0; r < 4; ++r) v[r] = acc[i][jj][r] * rinv;
      u32 h0, l0, h1, l1;
      split2(v[0], v[1], h0, l0);
      split2(v[2], v[3], h1, l1);
      uint2 H; H.x = h0; H.y = h1;
      uint2 L; L.x = l0; L.y = l1;
      *(uint2*)(Ehi + rowo + i * 16 + ro) = H;
      *(uint2*)(Elo + rowo + i * 16 + ro) = L;
      // colsum partials: reduce over the 16 n in this quarter-group
#pragma unroll
      for (int r = 0; r < 4; ++r) {
        float t = v[r];
        t += __shfl_xor(t, 1);
        t += __shfl_xor(t, 2);
        t += __shfl_xor(t, 4);
        t += __shfl_xor(t, 8);
        if ((lane & 15) == 0)
          atomicAdd(&colsum[b * M_ + i * 16 + ro + r], t);
      }
    }
  }
}

// ---------------------------------------------------------------------------
// BN batch stats: stats[c] = sum, stats[C_+c] = sumsq. grid = (C_, B_).
// ---------------------------------------------------------------------------
__global__ __launch_bounds__(256) void bnstats(
    const float* __restrict__ Y, float* __restrict__ stats) {
  const int c = blockIdx.x, b = blockIdx.y;
  const float4* p = (const float4*)(Y + ((size_t)b * C_ + c) * N_);
  float s = 0.0f, s2 = 0.0f;
  for (int i = threadIdx.x; i < N_ / 4; i += 256) {
    float4 v = p[i];
    s  += v.x + v.y + v.z + v.w;
    s2 += v.x * v.x + v.y * v.y + v.z * v.z + v.w * v.w;
  }
#pragma unroll
  for (int off = 32; off; off >>= 1) {
    s  += __shfl_xor(s, off);
    s2 += __shfl_xor(s2, off);
  }
  __shared__ float ws[2][4];
  const int lane = threadIdx.x & 63, wid = threadIdx.x >> 6;
  if (lane == 0) { ws[0][wid] = s; ws[1][wid] = s2; }
  __syncthreads();
  if (threadIdx.x == 0) {
    float ts = ws[0][0] + ws[0][1] + ws[0][2] + ws[0][3];
    float t2 = ws[1][0] + ws[1][1] + ws[1][2] + ws[1][3];
    atomicAdd(&stats[c], ts);
    atomicAdd(&stats[C_ + c], t2);
  }
}

// ---------------------------------------------------------------------------
// BN2 apply + ReLU + residual, transpose to split planes [n][c].
// grid = (N_/64, C_/64, B_)
// ---------------------------------------------------------------------------
__global__ __launch_bounds__(256) void bn_res_T(
    const float* __restrict__ Y, const float* __restrict__ X,
    const float* __restrict__ stats, const float* __restrict__ g,
    const float* __restrict__ bta,
    u16* __restrict__ Thi, u16* __restrict__ Tlo) {
  __shared__ u32 T[64][65];
  const int tid = threadIdx.x;
  const int n0 = blockIdx.x * 64, c0 = blockIdx.y * 64, b = blockIdx.z;
  const int cg = (tid & 15) * 4;
#pragma unroll
  for (int p = 0; p < 4; ++p) {
    const int r = p * 16 + (tid >> 4);
    const int c = c0 + r;
    const float mu  = stats[c] * (1.0f / CNT_);
    const float var = stats[C_ + c] * (1.0f / CNT_) - mu * mu;
    const float rs  = rsqrtf(var + EPS_BN);
    const float ga = g[c], be = bta[c];
    const size_t idx = ((size_t)b * C_ + c) * N_ + n0 + cg;
    float4 v  = *(const float4*)(Y + idx);
    float4 xv = *(const float4*)(X + idx);
    float4 t;
    t.x = fmaxf(ga * (v.x - mu) * rs + be, 0.0f) + xv.x;
    t.y = fmaxf(ga * (v.y - mu) * rs + be, 0.0f) + xv.y;
    t.z = fmaxf(ga * (v.z - mu) * rs + be, 0.0f) + xv.z;
    t.w = fmaxf(ga * (v.w - mu) * rs + be, 0.0f) + xv.w;
    T[r][cg + 0] = split_pack(t.x);
    T[r][cg + 1] = split_pack(t.y);
    T[r][cg + 2] = split_pack(t.z);
    T[r][cg + 3] = split_pack(t.w);
  }
  __syncthreads();
#pragma unroll
  for (int it = 0; it < 2; ++it) {
    const int s = it * 256 + tid;
    const int nl = s >> 3, cb = s & 7;
    u32 u[8];
#pragma unroll
    for (int j = 0; j < 8; ++j) u[j] = T[cb * 8 + j][nl];
    uint4 H, L;
    H.x = (u[0] & 0xFFFFu) | (u[1] << 16);
    H.y = (u[2] & 0xFFFFu) | (u[3] << 16);
    H.z = (u[4] & 0xFFFFu) | (u[5] << 16);
    H.w = (u[6] & 0xFFFFu) | (u[7] << 16);
    L.x = (u[0] >> 16) | (u[1] & 0xFFFF0000u);
    L.y = (u[2] >> 16) | (u[3] & 0xFFFF0000u);
    L.z = (u[4] >> 16) | (u[5] & 0xFFFF0000u);
    L.w = (u[6] >> 16) | (u[7] & 0xFFFF0000u);
    const size_t o = ((size_t)b * N_ + n0 + nl) * C_ + c0 + cb * 8;
    *(uint4*)(Thi + o) = H;
    *(uint4*)(Tlo + o) = L;
  }
}

// ---------------------------------------------------------------------------
// Final BN apply + ReLU (in place). grid = B_*C_*N_/(4*256)
// ---------------------------------------------------------------------------
__global__ __launch_bounds__(256) void bn_apply(
    const float* __restrict__ Y, const float* __restrict__ stats,
    const float* __restrict__ g, const float* __restrict__ bta,
    float* __restrict__ Out) {
  const size_t i = ((size_t)blockIdx.x * 256 + threadIdx.x) * 4;
  const int c = (int)((i >> 12) & (C_ - 1));
  const float mu  = stats[c] * (1.0f / CNT_);
  const float var = stats[C_ + c] * (1.0f / CNT_) - mu * mu;
  const float rs  = rsqrtf(var + EPS_BN);
  const float ga = g[c], be = bta[c];
  float4 y = *(const float4*)(Y + i);
  float4 o;
  o.x = fmaxf(ga * (y.x - mu) * rs + be, 0.0f);
  o.y = fmaxf(ga * (y.y - mu) * rs + be, 0.0f);
  o.z = fmaxf(ga * (y.z - mu) * rs + be, 0.0f);
  o.w = fmaxf(ga * (y.w - mu) * rs + be, 0.0f);
  *(float4*)(Out + i) = o;
}

// Zero the small stats region (colsum + stats2 + stats3 = 5120 floats)
__global__ __launch_bounds__(256) void zero_small(float* __restrict__ p) {
  p[blockIdx.x * 256 + threadIdx.x] = 0.0f;
}

// ---------------------------------------------------------------------------
extern "C" void kernel_launch(void* const* d_in, const int* in_sizes, int n_in,
                              void* d_out, int out_size, void* d_ws, size_t ws_size,
                              hipStream_t stream) {
  const float* x        = (const float*)d_in[0];
  const float* centers  = (const float*)d_in[1];
  const float* conv1_w  = (const float*)d_in[2];
  const float* conv1_b  = (const float*)d_in[3];
  const float* conv2_w  = (const float*)d_in[4];
  const float* bn2_g    = (const float*)d_in[5];
  const float* bn2_b    = (const float*)d_in[6];
  const float* conv3_w  = (const float*)d_in[7];
  const float* conv3_b  = (const float*)d_in[8];
  const float* bn3_g    = (const float*)d_in[9];
  const float* bn3_b    = (const float*)d_in[10];
  float* out = (float*)d_out;

  const size_t TENS = (size_t)B_ * C_ * N_;       // 33,554,432 elems
  char* w = (char*)d_ws;
  // region A (134MB): xT planes -> xreT planes -> tT planes
  u16* xThi = (u16*)w;
  u16* xTlo = xThi + TENS;
  // region B (134MB): x1T planes -> cent_scaled planes (after att) -> y2 fp32
  char* wB = w + 134217728;
  u16* x1Thi = (u16*)wB;
  u16* x1Tlo = x1Thi + TENS;
  u16* cshi  = (u16*)wB;                          // alias (x1T dead post-att)
  u16* cslo  = cshi + (size_t)B_ * C_ * M_;
  float* y2  = (float*)wB;                        // alias (cs dead post-conv2-read)
  // region C (50.3MB): e planes
  char* wC = w + 268435456;
  u16* Ehi = (u16*)wC;
  u16* Elo = Ehi + (size_t)B_ * N_ * M_;
  // region D: small + weight planes + centT planes
  char* wD = wC + 50331648;
  float* colsum = (float*)wD;                      // 3072
  float* stats2 = colsum + B_ * M_;                // 1024
  float* stats3 = stats2 + 2 * C_;                 // 1024
  u16* w1hi = (u16*)(stats3 + 2 * C_);
  u16* w1lo = w1hi + 262144;
  u16* w2hi = w1lo + 262144;
  u16* w2lo = w2hi + 262144;
  u16* w3hi = w2lo + 262144;
  u16* w3lo = w3hi + 262144;
  u16* cThi = w3lo + 262144;                       // [192][512]
  u16* cTlo = cThi + 98304;
  // region A aliases
  u16* xreThi = xThi; u16* xreTlo = xTlo;
  u16* tThi   = xThi; u16* tTlo   = xTlo;

  const dim3 gmm(N_ / 128, C_ / 128, B_);

  // 1. zero colsum + stats
  zero_small<<<20, 256, 0, stream>>>(colsum);
  // 2. weight planes
  convert_ew<<<256, 256, 0, stream>>>(conv1_w, w1hi, w1lo);
  convert_ew<<<256, 256, 0, stream>>>(conv2_w, w2hi, w2lo);
  convert_ew<<<256, 256, 0, stream>>>(conv3_w, w3hi, w3lo);
  // 3. centers^T planes
  centT_conv<<<384, 256, 0, stream>>>(centers, cThi, cTlo);
  // 4. x -> xT planes
  convert_x_T<<<dim3(N_ / 64, C_ / 64, B_), 256, 0, stream>>>(x, xThi, xTlo);
  // 5. conv1 -> x1T planes [n][o]
  mm_mfma<512, 1, false><<<gmm, 256, 0, stream>>>(
      w1hi, w1lo, xThi, xTlo, nullptr, x1Thi, x1Tlo, conv1_b);
  // 6. fused att: logits + softmax + colsum
  att_mfma<<<dim3(N_ / 128, 1, B_), 256, 0, stream>>>(
      cThi, cTlo, x1Thi, x1Tlo, Ehi, Elo, colsum);
  // 7. per-batch scaled centers
  cent_scale<<<dim3(384, B_), 256, 0, stream>>>(centers, colsum, cshi, cslo);
  // 8. xre: [c][n] = cent_scaled @ e^T -> xreT planes [n][c]
  mm_mfma<192, 1, true><<<gmm, 256, 0, stream>>>(
      cshi, cslo, Ehi, Elo, nullptr, xreThi, xreTlo, nullptr);
  // 9. conv2 -> y2 fp32 [o][n]
  mm_mfma<512, 0, false><<<gmm, 256, 0, stream>>>(
      w2hi, w2lo, xreThi, xreTlo, y2, nullptr, nullptr, nullptr);
  // 10. BN2 stats
  bnstats<<<dim3(C_, B_), 256, 0, stream>>>(y2, stats2);
  // 11. tT planes = relu(bn2(y2)) + x
  bn_res_T<<<dim3(N_ / 64, C_ / 64, B_), 256, 0, stream>>>(
      y2, x, stats2, bn2_g, bn2_b, tThi, tTlo);
  // 12. conv3 -> out fp32
  mm_mfma<512, 0, false><<<gmm, 256, 0, stream>>>(
      w3hi, w3lo, tThi, tTlo, out, nullptr, nullptr, conv3_b);
  // 13. BN3 stats
  bnstats<<<dim3(C_, B_), 256, 0, stream>>>(out, stats3);
  // 14. out = relu(bn3(out))
  bn_apply<<<(B_ * C_ * N_) / (4 * 256), 256, 0, stream>>>(
      out, stats3, bn3_g, bn3_b, out);
}